// Round 6
// baseline (221.124 us; speedup 1.0000x reference)
//
#include <hip/hip_runtime.h>
#include <math.h>

#define SEQ    4096
#define DMODEL 1024
#define NHEAD  16
#define DHEAD  64
#define KVHALF 2048           // keys per attention block (split-KV x2)

typedef __bf16 bf16;
typedef bf16  bf16x2 __attribute__((ext_vector_type(2)));
typedef bf16  bf16x4 __attribute__((ext_vector_type(4)));
typedef bf16  bf16x8 __attribute__((ext_vector_type(8)));
typedef float f32x4  __attribute__((ext_vector_type(4)));
typedef float f32x16 __attribute__((ext_vector_type(16)));
typedef unsigned int u32;

// involutive 16B-chunk swizzles
#define SWZ(r)  ((((r) >> 2) ^ (r)) & 7)                    // GEMM
#define SWZ3(r) (((r) ^ ((r) >> 2) ^ ((r) >> 3)) & 7)       // attn

__device__ __forceinline__ void gll16(const void* g, void* l) {
    __builtin_amdgcn_global_load_lds(
        (const __attribute__((address_space(1))) void*)g,
        (__attribute__((address_space(3))) void*)l, 16, 0, 0);
}

__device__ __forceinline__ u32 cvtpk(float lo, float hi) {
    u32 r;
    asm("v_cvt_pk_bf16_f32 %0, %1, %2" : "=v"(r) : "v"(lo), "v"(hi));
    return r;
}
__device__ __forceinline__ void pswap(u32& a, u32& b) {
    asm volatile("v_permlane32_swap_b32 %0, %1" : "+v"(a), "+v"(b));
}

// ---------------------------------------------------------------------------
// fp32 -> bf16 convert
// ---------------------------------------------------------------------------
__global__ __launch_bounds__(256)
void cvt_bf16(const float* __restrict__ s, bf16* __restrict__ d, int n)
{
    const int i = (blockIdx.x * 256 + threadIdx.x) * 8;
    if (i >= n) return;
    float4 a = *(const float4*)&s[i];
    float4 b = *(const float4*)&s[i + 4];
    bf16x8 v;
    v[0] = (bf16)a.x; v[1] = (bf16)a.y; v[2] = (bf16)a.z; v[3] = (bf16)a.w;
    v[4] = (bf16)b.x; v[5] = (bf16)b.y; v[6] = (bf16)b.z; v[7] = (bf16)b.w;
    *(bf16x8*)&d[i] = v;
}

// ---------------------------------------------------------------------------
// bf16 MFMA GEMM:  C[M][N] = A[M][K] * B[N][K]^T
// BM=64, BN=64, BK=64; 4 waves in 2x2, each wave 32x32 (2x2 16x16 frags).
// 1024 blocks -> 4 blocks/CU (vs 2 at BN=128).
// ---------------------------------------------------------------------------
template<int EPI>
__global__ __launch_bounds__(256)
void gemm_mfma(const bf16* __restrict__ A, const bf16* __restrict__ B,
               bf16* __restrict__ Cb, float* __restrict__ Cf,
               const float* __restrict__ res, int M, int N, int K)
{
    const int bm   = blockIdx.y * 64;
    const int bn   = blockIdx.x * 64;
    const int tid  = threadIdx.x;
    const int w    = tid >> 6;
    const int lane = tid & 63;
    const int lr   = lane & 15;
    const int lh   = lane >> 4;
    const int wr   = w >> 1;
    const int wc   = w & 1;
    const int lrow = lane >> 3;
    const int lch  = lane & 7;

    __shared__ bf16 As[64 * 64];
    __shared__ bf16 Bs[64 * 64];

    f32x4 acc[2][2] = {};

    for (int k0 = 0; k0 < K; k0 += 64) {
        __syncthreads();
        #pragma unroll
        for (int i = 0; i < 2; ++i) {
            const int r = (w * 2 + i) * 8 + lrow;
            gll16(A + (size_t)(bm + r) * K + k0 + ((lch ^ SWZ(r)) << 3),
                  &As[(w * 2 + i) * 512]);
        }
        #pragma unroll
        for (int i = 0; i < 2; ++i) {
            const int r = (w * 2 + i) * 8 + lrow;
            gll16(B + (size_t)(bn + r) * K + k0 + ((lch ^ SWZ(r)) << 3),
                  &Bs[(w * 2 + i) * 512]);
        }
        asm volatile("s_waitcnt vmcnt(0)" ::: "memory");
        __syncthreads();

        bf16x8 af[2][2], bfr[2][2];
        #pragma unroll
        for (int rt = 0; rt < 2; ++rt)
            #pragma unroll
            for (int s = 0; s < 2; ++s) {
                const int r = wr * 32 + rt * 16 + lr;
                af[rt][s] = *(const bf16x8*)&As[r * 64 + (((s * 4 + lh) ^ SWZ(r)) << 3)];
            }
        #pragma unroll
        for (int ct = 0; ct < 2; ++ct)
            #pragma unroll
            for (int s = 0; s < 2; ++s) {
                const int r = wc * 32 + ct * 16 + lr;
                bfr[ct][s] = *(const bf16x8*)&Bs[r * 64 + (((s * 4 + lh) ^ SWZ(r)) << 3)];
            }
        __builtin_amdgcn_s_setprio(1);
        #pragma unroll
        for (int rt = 0; rt < 2; ++rt)
            #pragma unroll
            for (int ct = 0; ct < 2; ++ct)
                #pragma unroll
                for (int s = 0; s < 2; ++s)
                    acc[rt][ct] = __builtin_amdgcn_mfma_f32_16x16x32_bf16(
                        af[rt][s], bfr[ct][s], acc[rt][ct], 0, 0, 0);
        __builtin_amdgcn_s_setprio(0);
    }

    #pragma unroll
    for (int rt = 0; rt < 2; ++rt)
        #pragma unroll
        for (int ct = 0; ct < 2; ++ct)
            #pragma unroll
            for (int r = 0; r < 4; ++r) {
                const int m = bm + wr * 32 + rt * 16 + lh * 4 + r;
                const int n = bn + wc * 32 + ct * 16 + lr;
                if (EPI == 0) {
                    Cb[(size_t)m * N + n] = (bf16)acc[rt][ct][r];
                } else {
                    Cf[(size_t)m * N + n] =
                        fmaxf(acc[rt][ct][r], 0.f) + res[(size_t)m * N + n];
                }
            }
}

// ---------------------------------------------------------------------------
// MFMA flash attention, swapped-QK^T (32x32x16), in-register softmax,
// split-KV x2: block handles 2048 keys, writes un-normalized bf16 partial
// O^T + fp32 row-sums. 1024 blocks -> 4 blocks/CU, 16 waves/CU.
// ---------------------------------------------------------------------------
__global__ __launch_bounds__(256)
void attn_mfma(const bf16* __restrict__ Q, const bf16* __restrict__ K,
               const bf16* __restrict__ V,
               bf16* __restrict__ Oa, bf16* __restrict__ Ob,
               float* __restrict__ La, float* __restrict__ Lb)
{
    // bijective XCD swizzle over 1024 blocks: 128 logical per XCD
    const int wg   = blockIdx.x;
    const int lgc  = (wg & 7) * 128 + (wg >> 3);
    const int half = lgc >> 9;
    const int h    = (lgc >> 5) & 15;
    const int q0   = (lgc & 31) * 128;
    const int c0   = half * KVHALF;

    bf16*  Op = half ? Ob : Oa;
    float* Lp = half ? Lb : La;

    const int tid  = threadIdx.x;
    const int w    = tid >> 6;
    const int lane = tid & 63;
    const int lo5  = lane & 31;
    const int hi   = lane >> 5;
    const int lrow = lane >> 3;
    const int lch  = lane & 7;

    __shared__ bf16 Ks[2][64 * 64];
    __shared__ bf16 Vt[2][64 * 64];

    const bf16* qrow = Q + (size_t)(q0 + w * 32 + lo5) * DMODEL + h * 64;
    bf16x8 qf[4];
    #pragma unroll
    for (int s = 0; s < 4; ++s)
        qf[s] = *(const bf16x8*)&qrow[s * 16 + hi * 8];

    f32x16 acc0 = {}, acc1 = {};
    float ls0 = 0.f, ls1 = 0.f;

    const int vk = (tid & 7) * 8;
    const int vd = (tid >> 3) * 2;

    const float SC = 0.18033688f;       // 0.125 * log2(e)

    // ---- prologue: stage first chunk of this half into buffer 0
    #pragma unroll
    for (int i = 0; i < 2; ++i) {
        const int r = (w * 2 + i) * 8 + lrow;
        gll16(K + (size_t)(c0 + r) * DMODEL + h * 64 + ((lch ^ SWZ3(r)) << 3),
              &Ks[0][(w * 2 + i) * 512]);
    }
    {
        bf16x2 u[8];
        #pragma unroll
        for (int i = 0; i < 8; ++i)
            u[i] = *(const bf16x2*)&V[(size_t)(c0 + vk + i) * DMODEL + h * 64 + vd];
        asm volatile("s_waitcnt vmcnt(0)" ::: "memory");
        bf16x8 v0, v1;
        #pragma unroll
        for (int i = 0; i < 8; ++i) { v0[i] = u[i][0]; v1[i] = u[i][1]; }
        *(bf16x8*)&Vt[0][(vd + 0) * 64 + (((tid & 7) ^ SWZ3(vd + 0)) << 3)] = v0;
        *(bf16x8*)&Vt[0][(vd + 1) * 64 + (((tid & 7) ^ SWZ3(vd + 1)) << 3)] = v1;
    }
    __syncthreads();

#define BODY(CUR, CN)                                                          \
    {                                                                          \
        const int cn = c0 + (((CN) - c0) & (KVHALF - 1));                      \
        _Pragma("unroll")                                                      \
        for (int i = 0; i < 2; ++i) {                                          \
            const int r = (w * 2 + i) * 8 + lrow;                              \
            gll16(K + (size_t)(cn + r) * DMODEL + h * 64 + ((lch ^ SWZ3(r)) << 3), \
                  &Ks[(CUR) ^ 1][(w * 2 + i) * 512]);                          \
        }                                                                      \
        bf16x2 u[8];                                                           \
        _Pragma("unroll")                                                      \
        for (int i = 0; i < 8; ++i)                                            \
            u[i] = *(const bf16x2*)&V[(size_t)(cn + vk + i) * DMODEL + h * 64 + vd]; \
        const bf16* Kc = Ks[CUR];                                              \
        f32x16 st0 = {}, st1 = {};                                             \
        __builtin_amdgcn_s_setprio(1);                                         \
        _Pragma("unroll")                                                      \
        for (int s = 0; s < 4; ++s) {                                          \
            const int r0 = lo5, r1 = 32 + lo5;                                 \
            bf16x8 kf0 = *(const bf16x8*)&Kc[r0 * 64 + (((s * 2 + hi) ^ SWZ3(r0)) << 3)]; \
            bf16x8 kf1 = *(const bf16x8*)&Kc[r1 * 64 + (((s * 2 + hi) ^ SWZ3(r1)) << 3)]; \
            st0 = __builtin_amdgcn_mfma_f32_32x32x16_bf16(kf0, qf[s], st0, 0, 0, 0); \
            st1 = __builtin_amdgcn_mfma_f32_32x32x16_bf16(kf1, qf[s], st1, 0, 0, 0); \
        }                                                                      \
        __builtin_amdgcn_s_setprio(0);                                         \
        float p[32];                                                           \
        float a0 = 0.f, a1 = 0.f, a2 = 0.f, a3 = 0.f;                          \
        _Pragma("unroll")                                                      \
        for (int r = 0; r < 16; ++r) {                                         \
            float s0 = fminf(st0[r] * SC, 50.f);                               \
            float s1 = fminf(st1[r] * SC, 50.f);                               \
            p[r]      = __builtin_amdgcn_exp2f(s0);                            \
            p[16 + r] = __builtin_amdgcn_exp2f(s1);                            \
            if (r & 1) { a1 += p[r]; a3 += p[16 + r]; }                        \
            else       { a0 += p[r]; a2 += p[16 + r]; }                        \
        }                                                                      \
        ls0 += a0 + a1; ls1 += a2 + a3;                                        \
        union { u32 wd[4]; bf16x8 v; } fr[4];                                  \
        _Pragma("unroll")                                                      \
        for (int ks = 0; ks < 4; ++ks) {                                       \
            const int b = (ks & 1) * 8 + (ks >> 1) * 16;                       \
            u32 A0 = cvtpk(p[b + 0], p[b + 1]);                                \
            u32 C0 = cvtpk(p[b + 2], p[b + 3]);                                \
            u32 B0 = cvtpk(p[b + 4], p[b + 5]);                                \
            u32 D0 = cvtpk(p[b + 6], p[b + 7]);                                \
            pswap(A0, B0);                                                     \
            pswap(C0, D0);                                                     \
            fr[ks].wd[0] = A0; fr[ks].wd[1] = C0;                              \
            fr[ks].wd[2] = B0; fr[ks].wd[3] = D0;                              \
        }                                                                      \
        const bf16* Vc = Vt[CUR];                                              \
        __builtin_amdgcn_s_setprio(1);                                         \
        _Pragma("unroll")                                                      \
        for (int ks = 0; ks < 4; ++ks) {                                       \
            const int r0 = lo5, r1 = 32 + lo5;                                 \
            bf16x8 vf0 = *(const bf16x8*)&Vc[r0 * 64 + (((ks * 2 + hi) ^ SWZ3(r0)) << 3)]; \
            bf16x8 vf1 = *(const bf16x8*)&Vc[r1 * 64 + (((ks * 2 + hi) ^ SWZ3(r1)) << 3)]; \
            acc0 = __builtin_amdgcn_mfma_f32_32x32x16_bf16(vf0, fr[ks].v, acc0, 0, 0, 0); \
            acc1 = __builtin_amdgcn_mfma_f32_32x32x16_bf16(vf1, fr[ks].v, acc1, 0, 0, 0); \
        }                                                                      \
        __builtin_amdgcn_s_setprio(0);                                         \
        asm volatile("s_waitcnt vmcnt(0)" ::: "memory");                       \
        {                                                                      \
            bf16x8 v0, v1;                                                     \
            _Pragma("unroll")                                                  \
            for (int i = 0; i < 8; ++i) { v0[i] = u[i][0]; v1[i] = u[i][1]; }  \
            bf16* Vn = Vt[(CUR) ^ 1];                                          \
            *(bf16x8*)&Vn[(vd + 0) * 64 + (((tid & 7) ^ SWZ3(vd + 0)) << 3)] = v0; \
            *(bf16x8*)&Vn[(vd + 1) * 64 + (((tid & 7) ^ SWZ3(vd + 1)) << 3)] = v1; \
        }                                                                      \
        __syncthreads();                                                       \
    }

    for (int c = c0; c < c0 + KVHALF; c += 128) {
        BODY(0, c + 64)
        BODY(1, c + 128)
    }
#undef BODY

    // per-row partial sum (this half's 2048 keys)
    float lt = ls0 + ls1;
    lt += __shfl_xor(lt, 32);
    Lp[h * SEQ + q0 + w * 32 + lo5] = lt;   // both hi lanes write same value

    // un-normalized O^T partial -> bf16
    bf16* orow = Op + (size_t)(q0 + w * 32 + lo5) * DMODEL + h * 64;
    #pragma unroll
    for (int g = 0; g < 4; ++g) {
        bf16x4 o4;
        o4[0] = (bf16)acc0[g * 4 + 0];
        o4[1] = (bf16)acc0[g * 4 + 1];
        o4[2] = (bf16)acc0[g * 4 + 2];
        o4[3] = (bf16)acc0[g * 4 + 3];
        *(bf16x4*)&orow[g * 8 + 4 * hi] = o4;
        bf16x4 o5;
        o5[0] = (bf16)acc1[g * 4 + 0];
        o5[1] = (bf16)acc1[g * 4 + 1];
        o5[2] = (bf16)acc1[g * 4 + 2];
        o5[3] = (bf16)acc1[g * 4 + 3];
        *(bf16x4*)&orow[32 + g * 8 + 4 * hi] = o5;
    }
}

// ---------------------------------------------------------------------------
// combine: AO = (Oa + Ob) / (La + Lb)
// ---------------------------------------------------------------------------
__global__ __launch_bounds__(256)
void combine(const bf16* __restrict__ Oa, const bf16* __restrict__ Ob,
             const float* __restrict__ La, const float* __restrict__ Lb,
             bf16* __restrict__ AO)
{
    const int e   = (blockIdx.x * 256 + threadIdx.x) * 8;
    const int row = e >> 10;
    const int hh  = (e >> 6) & 15;
    const float inv = 1.0f / (La[hh * SEQ + row] + Lb[hh * SEQ + row]);
    bf16x8 a = *(const bf16x8*)&Oa[e];
    bf16x8 b = *(const bf16x8*)&Ob[e];
    bf16x8 o;
    #pragma unroll
    for (int i = 0; i < 8; ++i)
        o[i] = (bf16)(((float)a[i] + (float)b[i]) * inv);
    *(bf16x8*)&AO[e] = o;
}

// ---------------------------------------------------------------------------
extern "C" void kernel_launch(void* const* d_in, const int* in_sizes, int n_in,
                              void* d_out, int out_size, void* d_ws, size_t ws_size,
                              hipStream_t stream)
{
    const float* q   = (const float*)d_in[0];
    const float* k   = (const float*)d_in[1];
    const float* v   = (const float*)d_in[2];
    const float* Wq  = (const float*)d_in[3];
    const float* Wk  = (const float*)d_in[4];
    const float* Wv  = (const float*)d_in[5];
    const float* Wfc = (const float*)d_in[6];
    float* out = (float*)d_out;

    const int EM = SEQ * DMODEL;      // 4M
    const int WM = DMODEL * DMODEL;   // 1M

    // layout (64 MB total): Wfcb | qb kb vb Wqb Wkb Wvb | Pq Pk Pv | AO
    bf16* Wfcb = (bf16*)d_ws;
    bf16* qb   = Wfcb + WM;
    bf16* kb   = qb + EM;
    bf16* vb   = kb + EM;
    bf16* Wqb  = vb + EM;
    bf16* Wkb  = Wqb + WM;
    bf16* Wvb  = Wkb + WM;
    bf16* Pq   = Wvb + WM;
    bf16* Pk   = Pq + EM;
    bf16* Pv   = Pk + EM;
    bf16* AO   = Pv + EM;

    // overlays (valid after the three projection GEMMs complete):
    bf16*  Oa = qb;            // EM bf16
    bf16*  Ob = kb;            // EM bf16
    float* La = (float*)vb;    // 64K fp32
    float* Lb = La + NHEAD * SEQ;

    cvt_bf16<<<EM / 2048, 256, 0, stream>>>(q,   qb,   EM);
    cvt_bf16<<<EM / 2048, 256, 0, stream>>>(k,   kb,   EM);
    cvt_bf16<<<EM / 2048, 256, 0, stream>>>(v,   vb,   EM);
    cvt_bf16<<<WM / 2048, 256, 0, stream>>>(Wq,  Wqb,  WM);
    cvt_bf16<<<WM / 2048, 256, 0, stream>>>(Wk,  Wkb,  WM);
    cvt_bf16<<<WM / 2048, 256, 0, stream>>>(Wv,  Wvb,  WM);
    cvt_bf16<<<WM / 2048, 256, 0, stream>>>(Wfc, Wfcb, WM);

    dim3 gg(DMODEL / 64, SEQ / 64);
    gemm_mfma<0><<<gg, 256, 0, stream>>>(qb, Wqb, Pq, nullptr, nullptr, SEQ, DMODEL, DMODEL);
    gemm_mfma<0><<<gg, 256, 0, stream>>>(kb, Wkb, Pk, nullptr, nullptr, SEQ, DMODEL, DMODEL);
    gemm_mfma<0><<<gg, 256, 0, stream>>>(vb, Wvb, Pv, nullptr, nullptr, SEQ, DMODEL, DMODEL);

    attn_mfma<<<1024, 256, 0, stream>>>(Pq, Pk, Pv, Oa, Ob, La, Lb);

    combine<<<EM / 2048, 256, 0, stream>>>(Oa, Ob, La, Lb, AO);

    gemm_mfma<1><<<gg, 256, 0, stream>>>(AO, Wfcb, nullptr, out, q, SEQ, DMODEL, DMODEL);
}

// Round 7
// 214.031 us; speedup vs baseline: 1.0331x; 1.0331x over previous
//
#include <hip/hip_runtime.h>
#include <math.h>

#define SEQ    4096
#define DMODEL 1024
#define NHEAD  16
#define DHEAD  64
#define KVHALF 2048           // keys per attention block (split-KV x2)

typedef __bf16 bf16;
typedef bf16  bf16x2 __attribute__((ext_vector_type(2)));
typedef bf16  bf16x4 __attribute__((ext_vector_type(4)));
typedef bf16  bf16x8 __attribute__((ext_vector_type(8)));
typedef float f32x4  __attribute__((ext_vector_type(4)));
typedef float f32x16 __attribute__((ext_vector_type(16)));
typedef unsigned int u32;

// involutive 16B-chunk swizzles
#define SWZ(r)  ((((r) >> 2) ^ (r)) & 7)                    // GEMM
#define SWZ3(r) (((r) ^ ((r) >> 2) ^ ((r) >> 3)) & 7)       // attn

__device__ __forceinline__ void gll16(const void* g, void* l) {
    __builtin_amdgcn_global_load_lds(
        (const __attribute__((address_space(1))) void*)g,
        (__attribute__((address_space(3))) void*)l, 16, 0, 0);
}

__device__ __forceinline__ u32 cvtpk(float lo, float hi) {
    u32 r;
    asm("v_cvt_pk_bf16_f32 %0, %1, %2" : "=v"(r) : "v"(lo), "v"(hi));
    return r;
}
__device__ __forceinline__ void pswap(u32& a, u32& b) {
    asm volatile("v_permlane32_swap_b32 %0, %1" : "+v"(a), "+v"(b));
}

// ---------------------------------------------------------------------------
// fp32 -> bf16 convert
// ---------------------------------------------------------------------------
__global__ __launch_bounds__(256)
void cvt_bf16(const float* __restrict__ s, bf16* __restrict__ d, int n)
{
    const int i = (blockIdx.x * 256 + threadIdx.x) * 8;
    if (i >= n) return;
    float4 a = *(const float4*)&s[i];
    float4 b = *(const float4*)&s[i + 4];
    bf16x8 v;
    v[0] = (bf16)a.x; v[1] = (bf16)a.y; v[2] = (bf16)a.z; v[3] = (bf16)a.w;
    v[4] = (bf16)b.x; v[5] = (bf16)b.y; v[6] = (bf16)b.z; v[7] = (bf16)b.w;
    *(bf16x8*)&d[i] = v;
}

// ---------------------------------------------------------------------------
// bf16 MFMA GEMM:  C[M][N] = A[M][K] * B[N][K]^T   (unchanged from R6)
// ---------------------------------------------------------------------------
template<int EPI>
__global__ __launch_bounds__(256)
void gemm_mfma(const bf16* __restrict__ A, const bf16* __restrict__ B,
               bf16* __restrict__ Cb, float* __restrict__ Cf,
               const float* __restrict__ res, int M, int N, int K)
{
    const int bm   = blockIdx.y * 64;
    const int bn   = blockIdx.x * 64;
    const int tid  = threadIdx.x;
    const int w    = tid >> 6;
    const int lane = tid & 63;
    const int lr   = lane & 15;
    const int lh   = lane >> 4;
    const int wr   = w >> 1;
    const int wc   = w & 1;
    const int lrow = lane >> 3;
    const int lch  = lane & 7;

    __shared__ bf16 As[64 * 64];
    __shared__ bf16 Bs[64 * 64];

    f32x4 acc[2][2] = {};

    for (int k0 = 0; k0 < K; k0 += 64) {
        __syncthreads();
        #pragma unroll
        for (int i = 0; i < 2; ++i) {
            const int r = (w * 2 + i) * 8 + lrow;
            gll16(A + (size_t)(bm + r) * K + k0 + ((lch ^ SWZ(r)) << 3),
                  &As[(w * 2 + i) * 512]);
        }
        #pragma unroll
        for (int i = 0; i < 2; ++i) {
            const int r = (w * 2 + i) * 8 + lrow;
            gll16(B + (size_t)(bn + r) * K + k0 + ((lch ^ SWZ(r)) << 3),
                  &Bs[(w * 2 + i) * 512]);
        }
        asm volatile("s_waitcnt vmcnt(0)" ::: "memory");
        __syncthreads();

        bf16x8 af[2][2], bfr[2][2];
        #pragma unroll
        for (int rt = 0; rt < 2; ++rt)
            #pragma unroll
            for (int s = 0; s < 2; ++s) {
                const int r = wr * 32 + rt * 16 + lr;
                af[rt][s] = *(const bf16x8*)&As[r * 64 + (((s * 4 + lh) ^ SWZ(r)) << 3)];
            }
        #pragma unroll
        for (int ct = 0; ct < 2; ++ct)
            #pragma unroll
            for (int s = 0; s < 2; ++s) {
                const int r = wc * 32 + ct * 16 + lr;
                bfr[ct][s] = *(const bf16x8*)&Bs[r * 64 + (((s * 4 + lh) ^ SWZ(r)) << 3)];
            }
        __builtin_amdgcn_s_setprio(1);
        #pragma unroll
        for (int rt = 0; rt < 2; ++rt)
            #pragma unroll
            for (int ct = 0; ct < 2; ++ct)
                #pragma unroll
                for (int s = 0; s < 2; ++s)
                    acc[rt][ct] = __builtin_amdgcn_mfma_f32_16x16x32_bf16(
                        af[rt][s], bfr[ct][s], acc[rt][ct], 0, 0, 0);
        __builtin_amdgcn_s_setprio(0);
    }

    #pragma unroll
    for (int rt = 0; rt < 2; ++rt)
        #pragma unroll
        for (int ct = 0; ct < 2; ++ct)
            #pragma unroll
            for (int r = 0; r < 4; ++r) {
                const int m = bm + wr * 32 + rt * 16 + lh * 4 + r;
                const int n = bn + wc * 32 + ct * 16 + lr;
                if (EPI == 0) {
                    Cb[(size_t)m * N + n] = (bf16)acc[rt][ct][r];
                } else {
                    Cf[(size_t)m * N + n] =
                        fmaxf(acc[rt][ct][r], 0.f) + res[(size_t)m * N + n];
                }
            }
}

// ---------------------------------------------------------------------------
// MFMA flash attention, swapped-QK^T (32x32x16), in-register softmax.
// Register-economized: S processed 32 keys at a time (st = one f32x16),
// exp2 in place, P packed one k-slice at a time. Forced 4 waves/SIMD.
// Split-KV x2: 1024 blocks -> 4 blocks/CU, 16 waves/CU.
// ---------------------------------------------------------------------------
__global__ __launch_bounds__(256, 4)
void attn_mfma(const bf16* __restrict__ Q, const bf16* __restrict__ K,
               const bf16* __restrict__ V,
               bf16* __restrict__ Oa, bf16* __restrict__ Ob,
               float* __restrict__ La, float* __restrict__ Lb)
{
    // bijective XCD swizzle over 1024 blocks: 128 logical per XCD
    const int wg   = blockIdx.x;
    const int lgc  = (wg & 7) * 128 + (wg >> 3);
    const int half = lgc >> 9;
    const int h    = (lgc >> 5) & 15;
    const int q0   = (lgc & 31) * 128;
    const int c0   = half * KVHALF;

    bf16*  Op = half ? Ob : Oa;
    float* Lp = half ? Lb : La;

    const int tid  = threadIdx.x;
    const int w    = tid >> 6;
    const int lane = tid & 63;
    const int lo5  = lane & 31;
    const int hi   = lane >> 5;
    const int lrow = lane >> 3;
    const int lch  = lane & 7;

    __shared__ bf16 Ks[2][64 * 64];
    __shared__ bf16 Vt[2][64 * 64];

    const bf16* qrow = Q + (size_t)(q0 + w * 32 + lo5) * DMODEL + h * 64;
    bf16x8 qf[4];
    #pragma unroll
    for (int s = 0; s < 4; ++s)
        qf[s] = *(const bf16x8*)&qrow[s * 16 + hi * 8];

    f32x16 acc0 = {}, acc1 = {};
    float lsum = 0.f;

    const int vk = (tid & 7) * 8;
    const int vd = (tid >> 3) * 2;

    const float SC = 0.18033688f;       // 0.125 * log2(e)

    // ---- prologue: stage first chunk of this half into buffer 0
    #pragma unroll
    for (int i = 0; i < 2; ++i) {
        const int r = (w * 2 + i) * 8 + lrow;
        gll16(K + (size_t)(c0 + r) * DMODEL + h * 64 + ((lch ^ SWZ3(r)) << 3),
              &Ks[0][(w * 2 + i) * 512]);
    }
    {
        bf16x2 u[8];
        #pragma unroll
        for (int i = 0; i < 8; ++i)
            u[i] = *(const bf16x2*)&V[(size_t)(c0 + vk + i) * DMODEL + h * 64 + vd];
        asm volatile("s_waitcnt vmcnt(0)" ::: "memory");
        bf16x8 v0, v1;
        #pragma unroll
        for (int i = 0; i < 8; ++i) { v0[i] = u[i][0]; v1[i] = u[i][1]; }
        *(bf16x8*)&Vt[0][(vd + 0) * 64 + (((tid & 7) ^ SWZ3(vd + 0)) << 3)] = v0;
        *(bf16x8*)&Vt[0][(vd + 1) * 64 + (((tid & 7) ^ SWZ3(vd + 1)) << 3)] = v1;
    }
    __syncthreads();

#define BODY(CUR, CN)                                                          \
    {                                                                          \
        const int cn = c0 + (((CN) - c0) & (KVHALF - 1));                      \
        _Pragma("unroll")                                                      \
        for (int i = 0; i < 2; ++i) {                                          \
            const int r = (w * 2 + i) * 8 + lrow;                              \
            gll16(K + (size_t)(cn + r) * DMODEL + h * 64 + ((lch ^ SWZ3(r)) << 3), \
                  &Ks[(CUR) ^ 1][(w * 2 + i) * 512]);                          \
        }                                                                      \
        bf16x2 u[8];                                                           \
        _Pragma("unroll")                                                      \
        for (int i = 0; i < 8; ++i)                                            \
            u[i] = *(const bf16x2*)&V[(size_t)(cn + vk + i) * DMODEL + h * 64 + vd]; \
        const bf16* Kc = Ks[CUR];                                              \
        const bf16* Vc = Vt[CUR];                                              \
        _Pragma("unroll")                                                      \
        for (int kh = 0; kh < 2; ++kh) {                                       \
            const int rr = kh * 32 + lo5;                                      \
            f32x16 st = {};                                                    \
            __builtin_amdgcn_s_setprio(1);                                     \
            _Pragma("unroll")                                                  \
            for (int s = 0; s < 4; ++s) {                                      \
                bf16x8 kf = *(const bf16x8*)&Kc[rr * 64 + (((s * 2 + hi) ^ SWZ3(rr)) << 3)]; \
                st = __builtin_amdgcn_mfma_f32_32x32x16_bf16(kf, qf[s], st, 0, 0, 0); \
            }                                                                  \
            __builtin_amdgcn_s_setprio(0);                                     \
            _Pragma("unroll")                                                  \
            for (int r = 0; r < 16; ++r)                                       \
                st[r] = __builtin_amdgcn_exp2f(fminf(st[r] * SC, 50.f));       \
            lsum += (((st[0] + st[1]) + (st[2] + st[3]))                       \
                   + ((st[4] + st[5]) + (st[6] + st[7])))                      \
                  + (((st[8] + st[9]) + (st[10] + st[11]))                     \
                   + ((st[12] + st[13]) + (st[14] + st[15])));                 \
            _Pragma("unroll")                                                  \
            for (int kk = 0; kk < 2; ++kk) {                                   \
                const int ks = kh * 2 + kk;                                    \
                const int b = kk * 8;                                          \
                u32 A0 = cvtpk(st[b + 0], st[b + 1]);                          \
                u32 C0 = cvtpk(st[b + 2], st[b + 3]);                          \
                u32 B0 = cvtpk(st[b + 4], st[b + 5]);                          \
                u32 D0 = cvtpk(st[b + 6], st[b + 7]);                          \
                pswap(A0, B0);                                                 \
                pswap(C0, D0);                                                 \
                union { u32 wd[4]; bf16x8 v; } fr;                             \
                fr.wd[0] = A0; fr.wd[1] = C0; fr.wd[2] = B0; fr.wd[3] = D0;    \
                bf16x8 vf0 = *(const bf16x8*)&Vc[lo5 * 64 + (((ks * 2 + hi) ^ SWZ3(lo5)) << 3)]; \
                bf16x8 vf1 = *(const bf16x8*)&Vc[(32 + lo5) * 64 + (((ks * 2 + hi) ^ SWZ3(32 + lo5)) << 3)]; \
                __builtin_amdgcn_s_setprio(1);                                 \
                acc0 = __builtin_amdgcn_mfma_f32_32x32x16_bf16(vf0, fr.v, acc0, 0, 0, 0); \
                acc1 = __builtin_amdgcn_mfma_f32_32x32x16_bf16(vf1, fr.v, acc1, 0, 0, 0); \
                __builtin_amdgcn_s_setprio(0);                                 \
            }                                                                  \
        }                                                                      \
        asm volatile("s_waitcnt vmcnt(0)" ::: "memory");                       \
        {                                                                      \
            bf16x8 v0, v1;                                                     \
            _Pragma("unroll")                                                  \
            for (int i = 0; i < 8; ++i) { v0[i] = u[i][0]; v1[i] = u[i][1]; }  \
            bf16* Vn = Vt[(CUR) ^ 1];                                          \
            *(bf16x8*)&Vn[(vd + 0) * 64 + (((tid & 7) ^ SWZ3(vd + 0)) << 3)] = v0; \
            *(bf16x8*)&Vn[(vd + 1) * 64 + (((tid & 7) ^ SWZ3(vd + 1)) << 3)] = v1; \
        }                                                                      \
        __syncthreads();                                                       \
    }

    for (int c = c0; c < c0 + KVHALF; c += 128) {
        BODY(0, c + 64)
        BODY(1, c + 128)
    }
#undef BODY

    // per-row partial sum (this half's 2048 keys)
    float lt = lsum;
    lt += __shfl_xor(lt, 32);
    Lp[h * SEQ + q0 + w * 32 + lo5] = lt;

    // un-normalized O^T partial -> bf16
    bf16* orow = Op + (size_t)(q0 + w * 32 + lo5) * DMODEL + h * 64;
    #pragma unroll
    for (int g = 0; g < 4; ++g) {
        bf16x4 o4;
        o4[0] = (bf16)acc0[g * 4 + 0];
        o4[1] = (bf16)acc0[g * 4 + 1];
        o4[2] = (bf16)acc0[g * 4 + 2];
        o4[3] = (bf16)acc0[g * 4 + 3];
        *(bf16x4*)&orow[g * 8 + 4 * hi] = o4;
        bf16x4 o5;
        o5[0] = (bf16)acc1[g * 4 + 0];
        o5[1] = (bf16)acc1[g * 4 + 1];
        o5[2] = (bf16)acc1[g * 4 + 2];
        o5[3] = (bf16)acc1[g * 4 + 3];
        *(bf16x4*)&orow[32 + g * 8 + 4 * hi] = o5;
    }
}

// ---------------------------------------------------------------------------
// combine: AO = (Oa + Ob) / (La + Lb)
// ---------------------------------------------------------------------------
__global__ __launch_bounds__(256)
void combine(const bf16* __restrict__ Oa, const bf16* __restrict__ Ob,
             const float* __restrict__ La, const float* __restrict__ Lb,
             bf16* __restrict__ AO)
{
    const int e   = (blockIdx.x * 256 + threadIdx.x) * 8;
    const int row = e >> 10;
    const int hh  = (e >> 6) & 15;
    const float inv = 1.0f / (La[hh * SEQ + row] + Lb[hh * SEQ + row]);
    bf16x8 a = *(const bf16x8*)&Oa[e];
    bf16x8 b = *(const bf16x8*)&Ob[e];
    bf16x8 o;
    #pragma unroll
    for (int i = 0; i < 8; ++i)
        o[i] = (bf16)(((float)a[i] + (float)b[i]) * inv);
    *(bf16x8*)&AO[e] = o;
}

// ---------------------------------------------------------------------------
extern "C" void kernel_launch(void* const* d_in, const int* in_sizes, int n_in,
                              void* d_out, int out_size, void* d_ws, size_t ws_size,
                              hipStream_t stream)
{
    const float* q   = (const float*)d_in[0];
    const float* k   = (const float*)d_in[1];
    const float* v   = (const float*)d_in[2];
    const float* Wq  = (const float*)d_in[3];
    const float* Wk  = (const float*)d_in[4];
    const float* Wv  = (const float*)d_in[5];
    const float* Wfc = (const float*)d_in[6];
    float* out = (float*)d_out;

    const int EM = SEQ * DMODEL;      // 4M
    const int WM = DMODEL * DMODEL;   // 1M

    // layout (64 MB total): Wfcb | qb kb vb Wqb Wkb Wvb | Pq Pk Pv | AO
    bf16* Wfcb = (bf16*)d_ws;
    bf16* qb   = Wfcb + WM;
    bf16* kb   = qb + EM;
    bf16* vb   = kb + EM;
    bf16* Wqb  = vb + EM;
    bf16* Wkb  = Wqb + WM;
    bf16* Wvb  = Wkb + WM;
    bf16* Pq   = Wvb + WM;
    bf16* Pk   = Pq + EM;
    bf16* Pv   = Pk + EM;
    bf16* AO   = Pv + EM;

    // overlays (valid after the three projection GEMMs complete):
    bf16*  Oa = qb;            // EM bf16
    bf16*  Ob = kb;            // EM bf16
    float* La = (float*)vb;    // 64K fp32
    float* Lb = La + NHEAD * SEQ;

    cvt_bf16<<<EM / 2048, 256, 0, stream>>>(q,   qb,   EM);
    cvt_bf16<<<EM / 2048, 256, 0, stream>>>(k,   kb,   EM);
    cvt_bf16<<<EM / 2048, 256, 0, stream>>>(v,   vb,   EM);
    cvt_bf16<<<WM / 2048, 256, 0, stream>>>(Wq,  Wqb,  WM);
    cvt_bf16<<<WM / 2048, 256, 0, stream>>>(Wk,  Wkb,  WM);
    cvt_bf16<<<WM / 2048, 256, 0, stream>>>(Wv,  Wvb,  WM);
    cvt_bf16<<<WM / 2048, 256, 0, stream>>>(Wfc, Wfcb, WM);

    dim3 gg(DMODEL / 64, SEQ / 64);
    gemm_mfma<0><<<gg, 256, 0, stream>>>(qb, Wqb, Pq, nullptr, nullptr, SEQ, DMODEL, DMODEL);
    gemm_mfma<0><<<gg, 256, 0, stream>>>(kb, Wkb, Pk, nullptr, nullptr, SEQ, DMODEL, DMODEL);
    gemm_mfma<0><<<gg, 256, 0, stream>>>(vb, Wvb, Pv, nullptr, nullptr, SEQ, DMODEL, DMODEL);

    attn_mfma<<<1024, 256, 0, stream>>>(Pq, Pk, Pv, Oa, Ob, La, Lb);

    combine<<<EM / 2048, 256, 0, stream>>>(Oa, Ob, La, Lb, AO);

    gemm_mfma<1><<<gg, 256, 0, stream>>>(AO, Wfcb, nullptr, out, q, SEQ, DMODEL, DMODEL);
}